// Round 11
// baseline (461.461 us; speedup 1.0000x reference)
//
#include <hip/hip_runtime.h>
#include <hip/hip_bf16.h>

#define Bc 512
#define Lc 512
#define Tc 128
#define NG 2           // independent batch-groups per block
#define GBG 16         // batches per group
#define GB (NG * GBG)  // 32 batches per block
#define PSTR 136       // padded tile row stride (u16 elems)
#define PBUF (GBG * PSTR)

typedef __attribute__((ext_vector_type(8))) short bf16x8;
typedef __attribute__((ext_vector_type(4))) float f32x4;
typedef __attribute__((ext_vector_type(2))) float f32x2;

__device__ __forceinline__ void bar_lgkm() {
  asm volatile("s_waitcnt lgkmcnt(0)\n\ts_barrier" ::: "memory");
}
__device__ __forceinline__ unsigned short f2bf_u(float f) {
  __hip_bfloat16 h = __float2bfloat16(f);
  unsigned short us;
  __builtin_memcpy(&us, &h, 2);
  return us;
}
__device__ __forceinline__ short f2bf(float f) { return (short)f2bf_u(f); }
__device__ __forceinline__ unsigned pk2(float a, float b) {
  return (unsigned)f2bf_u(a) | ((unsigned)f2bf_u(b) << 16);
}
__device__ __forceinline__ float bf_lo(unsigned u) { return __uint_as_float(u << 16); }
__device__ __forceinline__ float bf_hi(unsigned u) { return __uint_as_float(u & 0xffff0000u); }

__global__ __launch_bounds__(256, 1) __attribute__((amdgpu_waves_per_eu(1, 1)))
void crf_forward(const float* __restrict__ x,      // [B,L,T]
                 const float* __restrict__ trans,  // [T,T]
                 const float* __restrict__ startT, // [T]
                 const float* __restrict__ endT,   // [T]
                 const int*   __restrict__ labels, // [B,L]
                 const int*   __restrict__ mask,   // [B,L]
                 float* __restrict__ diff_out,     // [B]
                 float* __restrict__ msum_out)     // [B]
{
  __shared__ __align__(16) unsigned short Pl[NG][2][PBUF];
  __shared__ __align__(16) float r_s[NG][2][GBG];
  __shared__ __align__(16) unsigned char mT[NG][Lc][GBG];
  __shared__ __align__(16) float c_s[GB];
  __shared__ float score_s[GB];
  __shared__ float msum_s[GB];
  __shared__ float red[4][GBG];     // per wave

  const int tid  = threadIdx.x;     // 0..255 (4 waves)
  const int lane = tid & 63;
  const int w    = tid >> 6;        // wave 0..3
  const int g    = w >> 1;          // group 0/1
  const int wl   = w & 1;           // wave-in-group: cols [64wl, 64wl+64)
  const int crow = lane & 15;
  const int khi  = lane >> 4;       // 0..3
  const int bg0  = blockIdx.x * GB;
  const int bgrp = bg0 + g * GBG;

  // ---- stage transposed mask bytes ----
  for (int i = tid; i < GB * Lc; i += 256) {
    int bb = i >> 9, t = i & (Lc - 1);
    mT[bb >> 4][t][bb & 15] = (unsigned char)mask[(size_t)(bg0 + bb) * Lc + t];
  }

  // ---- gold-path score + msum: wave w handles block-local batches 8w..8w+7 ----
  for (int bb = 8 * w; bb < 8 * w + 8; ++bb) {
    const int bglob = bg0 + bb;
    const int* lbp = labels + (size_t)bglob * Lc;
    const int* mkp = mask + (size_t)bglob * Lc;
    const float* xrow = x + (size_t)bglob * Lc * Tc;
    float sp = 0.f, msp = 0.f;
    for (int t = lane; t < Lc; t += 64) {
      int l0 = lbp[t];
      int m0 = mkp[t];
      msp += (float)m0;
      if (t < Lc - 1) {
        int l1 = lbp[t + 1];
        float m1 = (float)mkp[t + 1];
        sp += trans[l0 * Tc + l1] * m1 + xrow[(size_t)t * Tc + l0] * (float)m0;
      }
    }
#pragma unroll
    for (int off = 32; off; off >>= 1) {
      sp += __shfl_xor(sp, off);
      msp += __shfl_xor(msp, off);
    }
    if (lane == 0) {
      int last_idx = (int)msp - 1;
      int lt = lbp[last_idx];
      score_s[bb] = sp + startT[lbp[0]] + endT[lt]
                  + xrow[(size_t)(Lc - 1) * Tc + lt] * (float)mkp[Lc - 1];
      msum_s[bb] = msp;
    }
  }

  // ---- E-frags (B-operand): wave's 64 cols as col-pairs; 16 frags = 64 VGPRs ----
  const int colA = 64 * wl + 2 * crow;
#define LOADE(U, Q, DA, DB) bf16x8 DA, DB; { \
    _Pragma("unroll") for (int e = 0; e < 8; ++e) { \
      const float* tp__ = trans + (32 * (Q) + 8 * khi + e) * Tc + colA + 32 * (U); \
      DA[e] = f2bf(__expf(tp__[0])); \
      DB[e] = f2bf(__expf(tp__[1])); } }
  LOADE(0, 0, eA00, eB00) LOADE(0, 1, eA01, eB01)
  LOADE(0, 2, eA02, eB02) LOADE(0, 3, eA03, eB03)
  LOADE(1, 0, eA10, eB10) LOADE(1, 1, eA11, eB11)
  LOADE(1, 2, eA12, eB12) LOADE(1, 3, eA13, eB13)
#undef LOADE

  // ---- per-lane constant offsets ----
  const int aoff  = crow * PSTR + 8 * khi;
  const int wbase = (4 * khi) * PSTR + colA;
  const float* xp0 = x + (size_t)(bgrp + 4 * khi + 0) * Lc * Tc + colA;
  const float* xp1 = x + (size_t)(bgrp + 4 * khi + 1) * Lc * Tc + colA;
  const float* xp2 = x + (size_t)(bgrp + 4 * khi + 2) * Lc * Tc + colA;
  const float* xp3 = x + (size_t)(bgrp + 4 * khi + 3) * Lc * Tc + colA;
  const bool rlane = (wl == 0) && (crow == 0);   // per group: 4 lanes own rescale/c

  __syncthreads();  // mT staged

  // ---- init: alpha_0 = start + x_0; exact renorm by alpha_0[b][0] ----
  f32x2 s0 = *(const f32x2*)&startT[colA];
  f32x2 s1 = *(const f32x2*)&startT[colA + 32];
  f32x2 i00 = s0 + *(const f32x2*)xp0;
  f32x2 i01 = s0 + *(const f32x2*)xp1;
  f32x2 i02 = s0 + *(const f32x2*)xp2;
  f32x2 i03 = s0 + *(const f32x2*)xp3;
  f32x2 i10 = s1 + *(const f32x2*)(xp0 + 32);
  f32x2 i11 = s1 + *(const f32x2*)(xp1 + 32);
  f32x2 i12 = s1 + *(const f32x2*)(xp2 + 32);
  f32x2 i13 = s1 + *(const f32x2*)(xp3 + 32);
  f32x4 aA0 = {i00.x, i01.x, i02.x, i03.x};
  if (rlane) *(f32x4*)&r_s[g][1][khi << 2] = aA0;   // alpha_0[b][0]
  __syncthreads();
  f32x4 cb = *(const f32x4*)&r_s[g][1][khi << 2];
  unsigned P0_0 = pk2(__expf(i00.x - cb.x), __expf(i00.y - cb.x));
  unsigned P0_1 = pk2(__expf(i01.x - cb.y), __expf(i01.y - cb.y));
  unsigned P0_2 = pk2(__expf(i02.x - cb.z), __expf(i02.y - cb.z));
  unsigned P0_3 = pk2(__expf(i03.x - cb.w), __expf(i03.y - cb.w));
  unsigned P1_0 = pk2(__expf(i10.x - cb.x), __expf(i10.y - cb.x));
  unsigned P1_1 = pk2(__expf(i11.x - cb.y), __expf(i11.y - cb.y));
  unsigned P1_2 = pk2(__expf(i12.x - cb.z), __expf(i12.y - cb.z));
  unsigned P1_3 = pk2(__expf(i13.x - cb.w), __expf(i13.y - cb.w));
  *(unsigned*)&Pl[g][1][wbase + 0 * PSTR +  0] = P0_0;
  *(unsigned*)&Pl[g][1][wbase + 0 * PSTR + 32] = P1_0;
  *(unsigned*)&Pl[g][1][wbase + 1 * PSTR +  0] = P0_1;
  *(unsigned*)&Pl[g][1][wbase + 1 * PSTR + 32] = P1_1;
  *(unsigned*)&Pl[g][1][wbase + 2 * PSTR +  0] = P0_2;
  *(unsigned*)&Pl[g][1][wbase + 2 * PSTR + 32] = P1_2;
  *(unsigned*)&Pl[g][1][wbase + 3 * PSTR +  0] = P0_3;
  *(unsigned*)&Pl[g][1][wbase + 3 * PSTR + 32] = P1_3;
  f32x4 c  = rlane ? cb : (f32x4){0.f, 0.f, 0.f, 0.f};
  f32x4 lr = {0.f, 0.f, 0.f, 0.f};
  __syncthreads();                  // cb consumed -> safe to overwrite r_s[g][1]
  if (rlane) {
    f32x4 one = {1.f, 1.f, 1.f, 1.f};
    *(f32x4*)&r_s[g][1][khi << 2] = one;
  }
  // ---- depth-2 x prefetch: set A holds t=1, set B holds t=2 ----
  f32x2 qA00, qA01, qA10, qA11, qA20, qA21, qA30, qA31;
  f32x2 qB00, qB01, qB10, qB11, qB20, qB21, qB30, qB31;
#define LOADQ(S, T) { size_t xo__ = (size_t)(T) * Tc;                          \
    q##S##00 = *(const f32x2*)(xp0 + xo__);                                    \
    q##S##01 = *(const f32x2*)(xp0 + xo__ + 32);                               \
    q##S##10 = *(const f32x2*)(xp1 + xo__);                                    \
    q##S##11 = *(const f32x2*)(xp1 + xo__ + 32);                               \
    q##S##20 = *(const f32x2*)(xp2 + xo__);                                    \
    q##S##21 = *(const f32x2*)(xp2 + xo__ + 32);                               \
    q##S##30 = *(const f32x2*)(xp3 + xo__);                                    \
    q##S##31 = *(const f32x2*)(xp3 + xo__ + 32); }
  LOADQ(A, 1)
  LOADQ(B, 2)
  __syncthreads();                  // Pl[g][1], r_s[g][1] visible

#define MFMA_(A, B, C_) C_ = __builtin_amdgcn_mfma_f32_16x16x32_bf16(A, B, C_, 0, 0, 0)
  // consume set S at step T (loaded at T-2), refill S for T+2
#define STEP(T, RB, WB, S) do {                                                \
    bf16x8 Af0 = *(const bf16x8*)&Pl[g][RB][aoff +  0];                        \
    bf16x8 Af1 = *(const bf16x8*)&Pl[g][RB][aoff + 32];                        \
    bf16x8 Af2 = *(const bf16x8*)&Pl[g][RB][aoff + 64];                        \
    bf16x8 Af3 = *(const bf16x8*)&Pl[g][RB][aoff + 96];                        \
    f32x4 rr = *(const f32x4*)&r_s[g][RB][khi << 2];                           \
    unsigned mw = *(const unsigned*)&mT[g][T][khi << 2];                       \
    f32x2 e00 = {__expf((q##S##00).x), __expf((q##S##00).y)};                  \
    f32x2 e01 = {__expf((q##S##01).x), __expf((q##S##01).y)};                  \
    f32x2 e10 = {__expf((q##S##10).x), __expf((q##S##10).y)};                  \
    f32x2 e11 = {__expf((q##S##11).x), __expf((q##S##11).y)};                  \
    f32x2 e20 = {__expf((q##S##20).x), __expf((q##S##20).y)};                  \
    f32x2 e21 = {__expf((q##S##21).x), __expf((q##S##21).y)};                  \
    f32x2 e30 = {__expf((q##S##30).x), __expf((q##S##30).y)};                  \
    f32x2 e31 = {__expf((q##S##31).x), __expf((q##S##31).y)};                  \
    { int tp__ = (T) + 2; if (tp__ > Lc - 1) tp__ = Lc - 1; LOADQ(S, tp__) }   \
    f32x4 CA0u = {0.f,0.f,0.f,0.f}, CA0v = {0.f,0.f,0.f,0.f};                  \
    f32x4 CB0u = {0.f,0.f,0.f,0.f}, CB0v = {0.f,0.f,0.f,0.f};                  \
    f32x4 CA1u = {0.f,0.f,0.f,0.f}, CA1v = {0.f,0.f,0.f,0.f};                  \
    f32x4 CB1u = {0.f,0.f,0.f,0.f}, CB1v = {0.f,0.f,0.f,0.f};                  \
    MFMA_(Af0, eA00, CA0u); MFMA_(Af2, eA02, CA0v);                            \
    MFMA_(Af0, eB00, CB0u); MFMA_(Af2, eB02, CB0v);                            \
    MFMA_(Af0, eA10, CA1u); MFMA_(Af2, eA12, CA1v);                            \
    MFMA_(Af0, eB10, CB1u); MFMA_(Af2, eB12, CB1v);                            \
    MFMA_(Af1, eA01, CA0u); MFMA_(Af3, eA03, CA0v);                            \
    MFMA_(Af1, eB01, CB0u); MFMA_(Af3, eB03, CB0v);                            \
    MFMA_(Af1, eA11, CA1u); MFMA_(Af3, eA13, CA1v);                            \
    MFMA_(Af1, eB11, CB1u); MFMA_(Af3, eB13, CB1v);                            \
    f32x4 CA0 = CA0u + CA0v, CB0 = CB0u + CB0v;                                \
    f32x4 CA1 = CA1u + CA1v, CB1 = CB1u + CB1v;                                \
    bool m0 = (mw & 0x1u) != 0, m1 = (mw & 0x100u) != 0;                       \
    bool m2 = (mw & 0x10000u) != 0, m3 = (mw & 0x1000000u) != 0;               \
    { unsigned nv;                                                             \
      nv = pk2(CA0.x * rr.x * e00.x, CB0.x * rr.x * e00.y); P0_0 = m0 ? nv : P0_0; \
      nv = pk2(CA1.x * rr.x * e01.x, CB1.x * rr.x * e01.y); P1_0 = m0 ? nv : P1_0; \
      nv = pk2(CA0.y * rr.y * e10.x, CB0.y * rr.y * e10.y); P0_1 = m1 ? nv : P0_1; \
      nv = pk2(CA1.y * rr.y * e11.x, CB1.y * rr.y * e11.y); P1_1 = m1 ? nv : P1_1; \
      nv = pk2(CA0.z * rr.z * e20.x, CB0.z * rr.z * e20.y); P0_2 = m2 ? nv : P0_2; \
      nv = pk2(CA1.z * rr.z * e21.x, CB1.z * rr.z * e21.y); P1_2 = m2 ? nv : P1_2; \
      nv = pk2(CA0.w * rr.w * e30.x, CB0.w * rr.w * e30.y); P0_3 = m3 ? nv : P0_3; \
      nv = pk2(CA1.w * rr.w * e31.x, CB1.w * rr.w * e31.y); P1_3 = m3 ? nv : P1_3; } \
    *(unsigned*)&Pl[g][WB][wbase + 0 * PSTR +  0] = P0_0;                      \
    *(unsigned*)&Pl[g][WB][wbase + 0 * PSTR + 32] = P1_0;                      \
    *(unsigned*)&Pl[g][WB][wbase + 1 * PSTR +  0] = P0_1;                      \
    *(unsigned*)&Pl[g][WB][wbase + 1 * PSTR + 32] = P1_1;                      \
    *(unsigned*)&Pl[g][WB][wbase + 2 * PSTR +  0] = P0_2;                      \
    *(unsigned*)&Pl[g][WB][wbase + 2 * PSTR + 32] = P1_2;                      \
    *(unsigned*)&Pl[g][WB][wbase + 3 * PSTR +  0] = P0_3;                      \
    *(unsigned*)&Pl[g][WB][wbase + 3 * PSTR + 32] = P1_3;                      \
    if (rlane) {                                                               \
      c.x += m0 ? lr.x : 0.f; c.y += m1 ? lr.y : 0.f;                          \
      c.z += m2 ? lr.z : 0.f; c.w += m3 ? lr.w : 0.f;                          \
      int E0 = (int)((__float_as_uint(CA0.x) >> 23) & 0xffu) - 127;            \
      int E1 = (int)((__float_as_uint(CA0.y) >> 23) & 0xffu) - 127;            \
      int E2 = (int)((__float_as_uint(CA0.z) >> 23) & 0xffu) - 127;            \
      int E3 = (int)((__float_as_uint(CA0.w) >> 23) & 0xffu) - 127;            \
      lr.x = (float)E0 * 0.6931471805599453f;                                  \
      lr.y = (float)E1 * 0.6931471805599453f;                                  \
      lr.z = (float)E2 * 0.6931471805599453f;                                  \
      lr.w = (float)E3 * 0.6931471805599453f;                                  \
      f32x4 rv;                                                                \
      rv.x = __uint_as_float((unsigned)(127 - E0) << 23);                      \
      rv.y = __uint_as_float((unsigned)(127 - E1) << 23);                      \
      rv.z = __uint_as_float((unsigned)(127 - E2) << 23);                      \
      rv.w = __uint_as_float((unsigned)(127 - E3) << 23);                      \
      *(f32x4*)&r_s[g][WB][khi << 2] = rv;                                     \
    }                                                                          \
    bar_lgkm();                                                                \
  } while (0)

  for (int t = 1; t < Lc; t += 2) {
    STEP(t, 1, 0, A);
    if (t + 1 < Lc) STEP(t + 1, 0, 1, B);
  }
#undef STEP
#undef MFMA_
#undef LOADQ

  // ---- logZ_b = c_b + log(sum_j Abar[b][j] * exp(end[j])) ----
  if (rlane) *(f32x4*)&c_s[g * GBG + (khi << 2)] = c;
  f32x2 ed0 = *(const f32x2*)&endT[colA];
  f32x2 ed1 = *(const f32x2*)&endT[colA + 32];
  f32x2 ee0 = {__expf(ed0.x), __expf(ed0.y)};
  f32x2 ee1 = {__expf(ed1.x), __expf(ed1.y)};
  f32x4 sres;
  sres.x = bf_lo(P0_0) * ee0.x + bf_hi(P0_0) * ee0.y + bf_lo(P1_0) * ee1.x + bf_hi(P1_0) * ee1.y;
  sres.y = bf_lo(P0_1) * ee0.x + bf_hi(P0_1) * ee0.y + bf_lo(P1_1) * ee1.x + bf_hi(P1_1) * ee1.y;
  sres.z = bf_lo(P0_2) * ee0.x + bf_hi(P0_2) * ee0.y + bf_lo(P1_2) * ee1.x + bf_hi(P1_2) * ee1.y;
  sres.w = bf_lo(P0_3) * ee0.x + bf_hi(P0_3) * ee0.y + bf_lo(P1_3) * ee1.x + bf_hi(P1_3) * ee1.y;
#pragma unroll
  for (int off = 1; off < 16; off <<= 1) {
    sres.x += __shfl_xor(sres.x, off);
    sres.y += __shfl_xor(sres.y, off);
    sres.z += __shfl_xor(sres.z, off);
    sres.w += __shfl_xor(sres.w, off);
  }
  if (crow == 0) *(f32x4*)&red[w][khi << 2] = sres;
  __syncthreads();
  if (tid < GB) {
    int gg = tid >> 4, bl = tid & 15;
    float tot = red[2 * gg][bl] + red[2 * gg + 1][bl];
    float logZ = c_s[tid] + __logf(tot);
    diff_out[bg0 + tid] = logZ - score_s[tid];
    msum_out[bg0 + tid] = msum_s[tid];
  }
}

__global__ __launch_bounds__(512)
void crf_final(const float* __restrict__ diff, const float* __restrict__ msum,
               float* __restrict__ out)
{
  __shared__ float sd[512];
  __shared__ float sm[512];
  int t = threadIdx.x;
  sd[t] = diff[t];
  sm[t] = msum[t];
  __syncthreads();
  for (int s = 256; s > 0; s >>= 1) {
    if (t < s) { sd[t] += sd[t + s]; sm[t] += sm[t + s]; }
    __syncthreads();
  }
  if (t == 0) out[0] = sd[0] / sm[0];
}

extern "C" void kernel_launch(void* const* d_in, const int* in_sizes, int n_in,
                              void* d_out, int out_size, void* d_ws, size_t ws_size,
                              hipStream_t stream) {
  const float* x      = (const float*)d_in[0];
  const float* trans  = (const float*)d_in[1];
  const float* startT = (const float*)d_in[2];
  const float* endT   = (const float*)d_in[3];
  const int*   labels = (const int*)d_in[4];
  const int*   mask   = (const int*)d_in[5];
  float* out = (float*)d_out;
  float* ws  = (float*)d_ws;
  float* diff = ws;        // [512]
  float* msum = ws + Bc;   // [512]

  crf_forward<<<dim3(Bc / GB), dim3(256), 0, stream>>>(
      x, trans, startT, endT, labels, mask, diff, msum);
  crf_final<<<dim3(1), dim3(512), 0, stream>>>(diff, msum, out);
}

// Round 12
// 338.831 us; speedup vs baseline: 1.3619x; 1.3619x over previous
//
#include <hip/hip_runtime.h>
#include <hip/hip_bf16.h>

#define Bc 512
#define Lc 512
#define Tc 128
#define NG 2            // independent batch-groups per block
#define GBG 16          // batches per group
#define GB (NG * GBG)   // 32 batches per block
#define NWG 8           // waves per group (16 waves/block -> 4 waves/SIMD)
#define PSTR 136        // padded tile row stride (u16 elems)
#define PBUF (GBG * PSTR)

typedef __attribute__((ext_vector_type(8))) short bf16x8;
typedef __attribute__((ext_vector_type(4))) float f32x4;

// raw barrier: drain LDS ops only; global prefetches stay in flight
__device__ __forceinline__ void bar_lgkm() {
  asm volatile("s_waitcnt lgkmcnt(0)\n\ts_barrier" ::: "memory");
}
__device__ __forceinline__ unsigned short f2bf_u(float f) {
  __hip_bfloat16 h = __float2bfloat16(f);
  unsigned short us;
  __builtin_memcpy(&us, &h, 2);
  return us;
}
__device__ __forceinline__ short f2bf(float f) { return (short)f2bf_u(f); }

__global__ __launch_bounds__(1024, 1)
void crf_forward(const float* __restrict__ x,      // [B,L,T]
                 const float* __restrict__ trans,  // [T,T]
                 const float* __restrict__ startT, // [T]
                 const float* __restrict__ endT,   // [T]
                 const int*   __restrict__ labels, // [B,L]
                 const int*   __restrict__ mask,   // [B,L]
                 float* __restrict__ diff_out,     // [B]
                 float* __restrict__ msum_out)     // [B]
{
  __shared__ __align__(16) unsigned short Pl[NG][2][PBUF]; // dbuf Abar bf16 [b][j]
  __shared__ __align__(16) float r_s[NG][2][GBG];          // dbuf rescale bcast
  __shared__ unsigned char anyz[NG][Lc];                   // any mask==0 this (g,t)
  __shared__ __align__(16) float c_s[GB];
  __shared__ float score_s[GB];
  __shared__ float msum_s[GB];
  __shared__ float red[NG][GBG][NWG];

  const int tid  = threadIdx.x;     // 0..1023 (16 waves)
  const int lane = tid & 63;
  const int w    = tid >> 6;        // wave 0..15
  const int g    = w >> 3;          // group 0/1
  const int wg   = w & 7;           // wave-in-group: j-tile [16wg, 16wg+16)
  const int crow = lane & 15;
  const int khi  = lane >> 4;       // 0..3
  const int bg0  = blockIdx.x * GB;
  const int bgrp = bg0 + g * GBG;
  const int jloc = 16 * wg + crow;  // 0..127

  // ---- stage anyz flags: thread tid covers (gg = tid>>9, t = tid&511) ----
  {
    int gg = tid >> 9, t = tid & (Lc - 1);
    unsigned zz = 0;
    for (int bb = 0; bb < GBG; ++bb)
      zz |= (unsigned)(mask[(size_t)(bg0 + gg * GBG + bb) * Lc + t] == 0);
    anyz[gg][t] = (unsigned char)zz;
  }

  // ---- gold-path score + msum: wave w handles block-local batches 2w, 2w+1 ----
  for (int bb = 2 * w; bb < 2 * w + 2; ++bb) {
    const int bglob = bg0 + bb;
    const int* lbp = labels + (size_t)bglob * Lc;
    const int* mkp = mask + (size_t)bglob * Lc;
    const float* xrow = x + (size_t)bglob * Lc * Tc;
    float sp = 0.f, msp = 0.f;
    for (int t = lane; t < Lc; t += 64) {
      int l0 = lbp[t];
      int m0 = mkp[t];
      msp += (float)m0;
      if (t < Lc - 1) {
        int l1 = lbp[t + 1];
        float m1 = (float)mkp[t + 1];
        sp += trans[l0 * Tc + l1] * m1 + xrow[(size_t)t * Tc + l0] * (float)m0;
      }
    }
#pragma unroll
    for (int off = 32; off; off >>= 1) {
      sp += __shfl_xor(sp, off);
      msp += __shfl_xor(msp, off);
    }
    if (lane == 0) {
      int last_idx = (int)msp - 1;
      int lt = lbp[last_idx];
      score_s[bb] = sp + startT[lbp[0]] + endT[lt]
                  + xrow[(size_t)(Lc - 1) * Tc + lt] * (float)mkp[Lc - 1];
      msum_s[bb] = msp;
    }
  }

  // ---- E fragments (B-operand): wave's 16-j slice; 16 VGPRs ----
  bf16x8 Bf0, Bf1, Bf2, Bf3;
  {
    const float* tp_ = trans + jloc;
#pragma unroll
    for (int e = 0; e < 8; ++e) Bf0[e] = f2bf(__expf(tp_[(8 * khi + e) * Tc]));
#pragma unroll
    for (int e = 0; e < 8; ++e) Bf1[e] = f2bf(__expf(tp_[(32 + 8 * khi + e) * Tc]));
#pragma unroll
    for (int e = 0; e < 8; ++e) Bf2[e] = f2bf(__expf(tp_[(64 + 8 * khi + e) * Tc]));
#pragma unroll
    for (int e = 0; e < 8; ++e) Bf3[e] = f2bf(__expf(tp_[(96 + 8 * khi + e) * Tc]));
  }

  // ---- per-lane constant offsets / pointers ----
  const int aoff = crow * PSTR + 8 * khi;     // A-frag: row=batch(crow), k=8khi+e
  const int woff = (4 * khi) * PSTR + jloc;   // C write: rows 4khi+r, col jloc
  const float* xp0 = x + (size_t)(bgrp + 4 * khi + 0) * Lc * Tc + jloc;
  const float* xp1 = x + (size_t)(bgrp + 4 * khi + 1) * Lc * Tc + jloc;
  const float* xp2 = x + (size_t)(bgrp + 4 * khi + 2) * Lc * Tc + jloc;
  const float* xp3 = x + (size_t)(bgrp + 4 * khi + 3) * Lc * Tc + jloc;
  const bool rlane = (wg == 0) && (crow == 0);  // per group: 4 lanes (jloc==0)

  __syncthreads();  // anyz staged, score_s/msum_s ready

  // ---- init: alpha_0 = start + x_0; exact renorm by alpha_0[b][0] ----
  float st_j = startT[jloc];
  float a00 = st_j + xp0[0];
  float a01 = st_j + xp1[0];
  float a02 = st_j + xp2[0];
  float a03 = st_j + xp3[0];
  if (rlane) {                       // these lanes have jloc==0
    f32x4 cv = {a00, a01, a02, a03};
    *(f32x4*)&r_s[g][1][khi << 2] = cv;
  }
  __syncthreads();
  f32x4 cb = *(const f32x4*)&r_s[g][1][khi << 2];
  float Ao0 = __expf(a00 - cb.x);
  float Ao1 = __expf(a01 - cb.y);
  float Ao2 = __expf(a02 - cb.z);
  float Ao3 = __expf(a03 - cb.w);
  Pl[g][1][woff + 0 * PSTR] = f2bf_u(Ao0);
  Pl[g][1][woff + 1 * PSTR] = f2bf_u(Ao1);
  Pl[g][1][woff + 2 * PSTR] = f2bf_u(Ao2);
  Pl[g][1][woff + 3 * PSTR] = f2bf_u(Ao3);
  f32x4 c  = rlane ? cb : (f32x4){0.f, 0.f, 0.f, 0.f};
  f32x4 lr = {0.f, 0.f, 0.f, 0.f};   // log of scale applied by CURRENT r (=1 at start)
  __syncthreads();                   // cb consumed -> safe to overwrite r_s[g][1]
  if (rlane) {
    f32x4 one = {1.f, 1.f, 1.f, 1.f};
    *(f32x4*)&r_s[g][1][khi << 2] = one;
  }
  // ---- depth-2 x prefetch ----
  float xA0 = xp0[1 * Tc], xA1 = xp1[1 * Tc], xA2 = xp2[1 * Tc], xA3 = xp3[1 * Tc];
  float xB0 = xp0[2 * Tc], xB1 = xp1[2 * Tc], xB2 = xp2[2 * Tc], xB3 = xp3[2 * Tc];
  __syncthreads();                   // Pl[g][1], r_s[g][1] visible

  // Step t: S = Abar @ E (f32 acc, 2+2 split chains); Abar' = S * r_stale * exp(x_t);
  // c += lr at use time (masked only on the rare anyz path); r = 2^-E(S[0]), lr = E*ln2.
#define MFMA_(A, B, C_) C_ = __builtin_amdgcn_mfma_f32_16x16x32_bf16(A, B, C_, 0, 0, 0)
#define STEP(T, RB, WB, XA0, XA1, XA2, XA3) do {                               \
    bf16x8 Af0 = *(const bf16x8*)&Pl[g][RB][aoff +  0];                        \
    bf16x8 Af1 = *(const bf16x8*)&Pl[g][RB][aoff + 32];                        \
    bf16x8 Af2 = *(const bf16x8*)&Pl[g][RB][aoff + 64];                        \
    bf16x8 Af3 = *(const bf16x8*)&Pl[g][RB][aoff + 96];                        \
    f32x4 rr = *(const f32x4*)&r_s[g][RB][khi << 2];                           \
    unsigned char az = anyz[g][T];                                             \
    float ex0 = __expf(XA0), ex1 = __expf(XA1);                                \
    float ex2 = __expf(XA2), ex3 = __expf(XA3);                                \
    { int tp__ = (T) + 2; if (tp__ > Lc - 1) tp__ = Lc - 1;                    \
      size_t xo__ = (size_t)tp__ * Tc;                                         \
      XA0 = xp0[xo__]; XA1 = xp1[xo__]; XA2 = xp2[xo__]; XA3 = xp3[xo__]; }    \
    f32x4 Ca = {0.f, 0.f, 0.f, 0.f};                                           \
    f32x4 Cb2 = {0.f, 0.f, 0.f, 0.f};                                          \
    MFMA_(Af0, Bf0, Ca);  MFMA_(Af2, Bf2, Cb2);                                \
    MFMA_(Af1, Bf1, Ca);  MFMA_(Af3, Bf3, Cb2);                                \
    f32x4 Cr = Ca + Cb2;                                                       \
    float v0 = Cr.x * rr.x * ex0;                                              \
    float v1 = Cr.y * rr.y * ex1;                                              \
    float v2 = Cr.z * rr.z * ex2;                                              \
    float v3 = Cr.w * rr.w * ex3;                                              \
    if (az) {  /* rare general-mask path */                                    \
      int m0 = mask[(size_t)(bgrp + 4 * khi + 0) * Lc + (T)];                  \
      int m1 = mask[(size_t)(bgrp + 4 * khi + 1) * Lc + (T)];                  \
      int m2 = mask[(size_t)(bgrp + 4 * khi + 2) * Lc + (T)];                  \
      int m3 = mask[(size_t)(bgrp + 4 * khi + 3) * Lc + (T)];                  \
      Ao0 = m0 ? v0 : Ao0; Ao1 = m1 ? v1 : Ao1;                                \
      Ao2 = m2 ? v2 : Ao2; Ao3 = m3 ? v3 : Ao3;                                \
      if (rlane) {                                                             \
        c.x += m0 ? lr.x : 0.f; c.y += m1 ? lr.y : 0.f;                        \
        c.z += m2 ? lr.z : 0.f; c.w += m3 ? lr.w : 0.f;                        \
      }                                                                        \
    } else {                                                                   \
      Ao0 = v0; Ao1 = v1; Ao2 = v2; Ao3 = v3;                                  \
      if (rlane) { c.x += lr.x; c.y += lr.y; c.z += lr.z; c.w += lr.w; }       \
    }                                                                          \
    Pl[g][WB][woff + 0 * PSTR] = f2bf_u(Ao0);                                  \
    Pl[g][WB][woff + 1 * PSTR] = f2bf_u(Ao1);                                  \
    Pl[g][WB][woff + 2 * PSTR] = f2bf_u(Ao2);                                  \
    Pl[g][WB][woff + 3 * PSTR] = f2bf_u(Ao3);                                  \
    if (rlane) {                                                               \
      int E0 = (int)((__float_as_uint(Cr.x) >> 23) & 0xffu) - 127;             \
      int E1 = (int)((__float_as_uint(Cr.y) >> 23) & 0xffu) - 127;             \
      int E2 = (int)((__float_as_uint(Cr.z) >> 23) & 0xffu) - 127;             \
      int E3 = (int)((__float_as_uint(Cr.w) >> 23) & 0xffu) - 127;             \
      lr.x = (float)E0 * 0.6931471805599453f;                                  \
      lr.y = (float)E1 * 0.6931471805599453f;                                  \
      lr.z = (float)E2 * 0.6931471805599453f;                                  \
      lr.w = (float)E3 * 0.6931471805599453f;                                  \
      f32x4 rv;                                                                \
      rv.x = __uint_as_float((unsigned)(127 - E0) << 23);                      \
      rv.y = __uint_as_float((unsigned)(127 - E1) << 23);                      \
      rv.z = __uint_as_float((unsigned)(127 - E2) << 23);                      \
      rv.w = __uint_as_float((unsigned)(127 - E3) << 23);                      \
      *(f32x4*)&r_s[g][WB][khi << 2] = rv;                                     \
    }                                                                          \
    bar_lgkm();                                                                \
  } while (0)

  for (int t = 1; t < Lc; t += 2) {
    STEP(t, 1, 0, xA0, xA1, xA2, xA3);
    if (t + 1 < Lc) STEP(t + 1, 0, 1, xB0, xB1, xB2, xB3);
  }
#undef STEP
#undef MFMA_

  // ---- logZ_b = c_b + log(sum_j Abar[b][j] * exp(end[j])) ----
  if (rlane) *(f32x4*)&c_s[g * GBG + (khi << 2)] = c;
  float eex = __expf(endT[jloc]);
  float s0 = Ao0 * eex, s1 = Ao1 * eex, s2 = Ao2 * eex, s3 = Ao3 * eex;
#pragma unroll
  for (int off = 1; off < 16; off <<= 1) {
    s0 += __shfl_xor(s0, off);
    s1 += __shfl_xor(s1, off);
    s2 += __shfl_xor(s2, off);
    s3 += __shfl_xor(s3, off);
  }
  if (crow == 0) {
    red[g][4 * khi + 0][wg] = s0;
    red[g][4 * khi + 1][wg] = s1;
    red[g][4 * khi + 2][wg] = s2;
    red[g][4 * khi + 3][wg] = s3;
  }
  __syncthreads();
  if (tid < GB) {
    int gg = tid >> 4, bl = tid & 15;
    float tot = 0.f;
#pragma unroll
    for (int ww = 0; ww < NWG; ++ww) tot += red[gg][bl][ww];
    float logZ = c_s[tid] + __logf(tot);
    diff_out[bg0 + tid] = logZ - score_s[tid];
    msum_out[bg0 + tid] = msum_s[tid];
  }
}

__global__ __launch_bounds__(512)
void crf_final(const float* __restrict__ diff, const float* __restrict__ msum,
               float* __restrict__ out)
{
  __shared__ float sd[512];
  __shared__ float sm[512];
  int t = threadIdx.x;
  sd[t] = diff[t];
  sm[t] = msum[t];
  __syncthreads();
  for (int s = 256; s > 0; s >>= 1) {
    if (t < s) { sd[t] += sd[t + s]; sm[t] += sm[t + s]; }
    __syncthreads();
  }
  if (t == 0) out[0] = sd[0] / sm[0];
}

extern "C" void kernel_launch(void* const* d_in, const int* in_sizes, int n_in,
                              void* d_out, int out_size, void* d_ws, size_t ws_size,
                              hipStream_t stream) {
  const float* x      = (const float*)d_in[0];
  const float* trans  = (const float*)d_in[1];
  const float* startT = (const float*)d_in[2];
  const float* endT   = (const float*)d_in[3];
  const int*   labels = (const int*)d_in[4];
  const int*   mask   = (const int*)d_in[5];
  float* out = (float*)d_out;
  float* ws  = (float*)d_ws;
  float* diff = ws;        // [512]
  float* msum = ws + Bc;   // [512]

  crf_forward<<<dim3(Bc / GB), dim3(1024), 0, stream>>>(
      x, trans, startT, endT, labels, mask, diff, msum);
  crf_final<<<dim3(1), dim3(512), 0, stream>>>(diff, msum, out);
}

// Round 13
// 197.867 us; speedup vs baseline: 2.3322x; 1.7124x over previous
//
#include <hip/hip_runtime.h>
#include <hip/hip_bf16.h>

#define Bc 512
#define Lc 512
#define Tc 128
#define GB 16     // batches per block
#define NW 8      // waves per block
#define PSTR 136  // padded P row stride in bf16 elems (272B = 17*16B)
#define PBUF (GB * PSTR)

typedef __attribute__((ext_vector_type(8))) short bf16x8;
typedef __attribute__((ext_vector_type(4))) float f32x4;

// raw barrier: drain LDS ops only; global prefetches stay in flight
__device__ __forceinline__ void bar_lgkm() {
  asm volatile("s_waitcnt lgkmcnt(0)\n\ts_barrier" ::: "memory");
}
__device__ __forceinline__ unsigned short f2bf_u(float f) {
  __hip_bfloat16 h = __float2bfloat16(f);
  unsigned short us;
  __builtin_memcpy(&us, &h, 2);
  return us;
}
__device__ __forceinline__ short f2bf(float f) { return (short)f2bf_u(f); }

__global__ __launch_bounds__(512, 1)
void crf_forward(const float* __restrict__ x,      // [B,L,T]
                 const float* __restrict__ trans,  // [T,T]
                 const float* __restrict__ startT, // [T]
                 const float* __restrict__ endT,   // [T]
                 const int*   __restrict__ labels, // [B,L]
                 const int*   __restrict__ mask,   // [B,L]
                 float* __restrict__ diff_out,     // [B]
                 float* __restrict__ msum_out)     // [B]
{
  __shared__ __align__(16) unsigned short Pl[2 * PBUF]; // double-buffered Abar bf16 [b][j]
  __shared__ __align__(16) float r_s[GB];               // rescale bcast (1 in 4 steps)
  __shared__ unsigned char anyz[Lc];                    // any mask==0 at t
  __shared__ __align__(16) float c_s[GB];
  __shared__ float score_s[GB];
  __shared__ float msum_s[GB];
  __shared__ float red[GB][NW];

  const int tid  = threadIdx.x;
  const int lane = tid & 63;
  const int w    = tid >> 6;        // wave 0..7 owns j-tile [16w,16w+16)
  const int crow = lane & 15;
  const int khi  = lane >> 4;       // 0..3
  const int bg0  = blockIdx.x * GB;
  const int jloc = 16 * w + crow;   // 0..127

  // ---- stage anyz flags (one-time) ----
  if (tid < Lc) {
    unsigned zz = 0;
    for (int bb = 0; bb < GB; ++bb)
      zz |= (unsigned)(mask[(size_t)(bg0 + bb) * Lc + tid] == 0);
    anyz[tid] = (unsigned char)zz;
  }

  // ---- gold-path score + msum: wave w handles local batches 2w, 2w+1 ----
  for (int bb = 2 * w; bb < 2 * w + 2; ++bb) {
    const int bglob = bg0 + bb;
    const int* lbp = labels + (size_t)bglob * Lc;
    const int* mkp = mask + (size_t)bglob * Lc;
    const float* xrow = x + (size_t)bglob * Lc * Tc;
    float sp = 0.f, msp = 0.f;
    for (int t = lane; t < Lc; t += 64) {
      int l0 = lbp[t];
      int m0 = mkp[t];
      msp += (float)m0;
      if (t < Lc - 1) {
        int l1 = lbp[t + 1];
        float m1 = (float)mkp[t + 1];
        sp += trans[l0 * Tc + l1] * m1 + xrow[(size_t)t * Tc + l0] * (float)m0;
      }
    }
#pragma unroll
    for (int off = 32; off; off >>= 1) {
      sp += __shfl_xor(sp, off);
      msp += __shfl_xor(msp, off);
    }
    if (lane == 0) {
      int last_idx = (int)msp - 1;
      int lt = lbp[last_idx];
      score_s[bb] = sp + startT[lbp[0]] + endT[lt]
                  + xrow[(size_t)(Lc - 1) * Tc + lt] * (float)mkp[Lc - 1];
      msum_s[bb] = msp;
    }
  }

  // ---- E fragments (B-operand): wave's 16-j slice; 16 VGPRs ----
  bf16x8 Bf0, Bf1, Bf2, Bf3;
  {
    const float* tp_ = trans + jloc;
#pragma unroll
    for (int e = 0; e < 8; ++e) Bf0[e] = f2bf(__expf(tp_[(8 * khi + e) * Tc]));
#pragma unroll
    for (int e = 0; e < 8; ++e) Bf1[e] = f2bf(__expf(tp_[(32 + 8 * khi + e) * Tc]));
#pragma unroll
    for (int e = 0; e < 8; ++e) Bf2[e] = f2bf(__expf(tp_[(64 + 8 * khi + e) * Tc]));
#pragma unroll
    for (int e = 0; e < 8; ++e) Bf3[e] = f2bf(__expf(tp_[(96 + 8 * khi + e) * Tc]));
  }

  // ---- per-lane constant offsets / pointers ----
  const int aoff = crow * PSTR + 8 * khi;     // A-frag: row=batch(crow), k=8khi+e
  const int woff = (4 * khi) * PSTR + jloc;   // C write: rows 4khi+r, col jloc
  const float* xp0 = x + (size_t)(bg0 + 4 * khi + 0) * Lc * Tc + jloc;
  const float* xp1 = x + (size_t)(bg0 + 4 * khi + 1) * Lc * Tc + jloc;
  const float* xp2 = x + (size_t)(bg0 + 4 * khi + 2) * Lc * Tc + jloc;
  const float* xp3 = x + (size_t)(bg0 + 4 * khi + 3) * Lc * Tc + jloc;
  const bool rlane = (w == 0) && (crow == 0); // 4 lanes own rescale/c (jloc==0)

  __syncthreads();  // anyz staged

  // ---- init: alpha_0 = start + x_0; exact renorm by alpha_0[b][0] ----
  float st_j = startT[jloc];
  float a00 = st_j + xp0[0];
  float a01 = st_j + xp1[0];
  float a02 = st_j + xp2[0];
  float a03 = st_j + xp3[0];
  if (rlane) {                      // these lanes have jloc==0
    f32x4 cv = {a00, a01, a02, a03};
    *(f32x4*)&r_s[khi << 2] = cv;
  }
  __syncthreads();
  f32x4 cb = *(const f32x4*)&r_s[khi << 2];
  float Ao0 = __expf(a00 - cb.x);
  float Ao1 = __expf(a01 - cb.y);
  float Ao2 = __expf(a02 - cb.z);
  float Ao3 = __expf(a03 - cb.w);
  Pl[PBUF + woff + 0 * PSTR] = f2bf_u(Ao0);
  Pl[PBUF + woff + 1 * PSTR] = f2bf_u(Ao1);
  Pl[PBUF + woff + 2 * PSTR] = f2bf_u(Ao2);
  Pl[PBUF + woff + 3 * PSTR] = f2bf_u(Ao3);
  f32x4 c  = rlane ? cb : (f32x4){0.f, 0.f, 0.f, 0.f};
  f32x4 lr = {0.f, 0.f, 0.f, 0.f};  // pending c-increment for next APPLY
  __syncthreads();                  // cb consumed -> safe to overwrite r_s
  if (rlane) {
    f32x4 one = {1.f, 1.f, 1.f, 1.f};
    *(f32x4*)&r_s[khi << 2] = one;  // first APPLY (t=1) multiplies by 1
  }
  // ---- depth-2 x prefetch ----
  float xA0 = xp0[1 * Tc], xA1 = xp1[1 * Tc], xA2 = xp2[1 * Tc], xA3 = xp3[1 * Tc];
  float xB0 = xp0[2 * Tc], xB1 = xp1[2 * Tc], xB2 = xp2[2 * Tc], xB3 = xp3[2 * Tc];
  __syncthreads();                  // Pl[1], r_s visible

  // Phases (PH): 1=APPLY (read r_s, scale, c+=lr), 2=PLAIN, 0=COMPUTE (rlane:
  // extract exponent of new Ao[b][0] -> r_s, lr). Mask: fast path unconditional;
  // az-flagged steps take the general masked path (per-batch freeze + c skip).
#define MFMA_(A, B, C_) C_ = __builtin_amdgcn_mfma_f32_16x16x32_bf16(A, B, C_, 0, 0, 0)
#define STEP(T, RB, WB, PH, XA0, XA1, XA2, XA3) do {                           \
    bf16x8 Af0 = *(const bf16x8*)&Pl[(RB) * PBUF + aoff +  0];                 \
    bf16x8 Af1 = *(const bf16x8*)&Pl[(RB) * PBUF + aoff + 32];                 \
    bf16x8 Af2 = *(const bf16x8*)&Pl[(RB) * PBUF + aoff + 64];                 \
    bf16x8 Af3 = *(const bf16x8*)&Pl[(RB) * PBUF + aoff + 96];                 \
    unsigned char az = anyz[T];                                                \
    float ex0 = __expf(XA0), ex1 = __expf(XA1);                                \
    float ex2 = __expf(XA2), ex3 = __expf(XA3);                                \
    { int tp__ = (T) + 2; if (tp__ > Lc - 1) tp__ = Lc - 1;                    \
      size_t xo__ = (size_t)tp__ * Tc;                                         \
      XA0 = xp0[xo__]; XA1 = xp1[xo__]; XA2 = xp2[xo__]; XA3 = xp3[xo__]; }    \
    f32x4 Ca = {0.f, 0.f, 0.f, 0.f};                                           \
    f32x4 Cb2 = {0.f, 0.f, 0.f, 0.f};                                          \
    MFMA_(Af0, Bf0, Ca);  MFMA_(Af2, Bf2, Cb2);                                \
    MFMA_(Af1, Bf1, Ca);  MFMA_(Af3, Bf3, Cb2);                                \
    f32x4 Cr = Ca + Cb2;                                                       \
    float v0, v1, v2, v3;                                                      \
    if ((PH) == 1) {                                                           \
      f32x4 rr = *(const f32x4*)&r_s[khi << 2];                                \
      v0 = Cr.x * rr.x * ex0; v1 = Cr.y * rr.y * ex1;                          \
      v2 = Cr.z * rr.z * ex2; v3 = Cr.w * rr.w * ex3;                          \
    } else {                                                                   \
      v0 = Cr.x * ex0; v1 = Cr.y * ex1;                                        \
      v2 = Cr.z * ex2; v3 = Cr.w * ex3;                                        \
    }                                                                          \
    if (az) {  /* rare general-mask path */                                    \
      int m0 = mask[(size_t)(bg0 + 4 * khi + 0) * Lc + (T)];                   \
      int m1 = mask[(size_t)(bg0 + 4 * khi + 1) * Lc + (T)];                   \
      int m2 = mask[(size_t)(bg0 + 4 * khi + 2) * Lc + (T)];                   \
      int m3 = mask[(size_t)(bg0 + 4 * khi + 3) * Lc + (T)];                   \
      Ao0 = m0 ? v0 : Ao0; Ao1 = m1 ? v1 : Ao1;                                \
      Ao2 = m2 ? v2 : Ao2; Ao3 = m3 ? v3 : Ao3;                                \
      if ((PH) == 1 && rlane) {                                                \
        c.x += m0 ? lr.x : 0.f; c.y += m1 ? lr.y : 0.f;                        \
        c.z += m2 ? lr.z : 0.f; c.w += m3 ? lr.w : 0.f;                        \
      }                                                                        \
    } else {                                                                   \
      Ao0 = v0; Ao1 = v1; Ao2 = v2; Ao3 = v3;                                  \
      if ((PH) == 1 && rlane) {                                                \
        c.x += lr.x; c.y += lr.y; c.z += lr.z; c.w += lr.w;                    \
      }                                                                        \
    }                                                                          \
    Pl[(WB) * PBUF + woff + 0 * PSTR] = f2bf_u(Ao0);                           \
    Pl[(WB) * PBUF + woff + 1 * PSTR] = f2bf_u(Ao1);                           \
    Pl[(WB) * PBUF + woff + 2 * PSTR] = f2bf_u(Ao2);                           \
    Pl[(WB) * PBUF + woff + 3 * PSTR] = f2bf_u(Ao3);                           \
    if ((PH) == 0 && rlane) {  /* COMPUTE: exponent of new Ao[b][0] */         \
      int E0 = (int)((__float_as_uint(Ao0) >> 23) & 0xffu) - 127;              \
      int E1 = (int)((__float_as_uint(Ao1) >> 23) & 0xffu) - 127;              \
      int E2 = (int)((__float_as_uint(Ao2) >> 23) & 0xffu) - 127;              \
      int E3 = (int)((__float_as_uint(Ao3) >> 23) & 0xffu) - 127;              \
      lr.x = (float)E0 * 0.6931471805599453f;                                  \
      lr.y = (float)E1 * 0.6931471805599453f;                                  \
      lr.z = (float)E2 * 0.6931471805599453f;                                  \
      lr.w = (float)E3 * 0.6931471805599453f;                                  \
      f32x4 rv;                                                                \
      rv.x = __uint_as_float((unsigned)(127 - E0) << 23);                      \
      rv.y = __uint_as_float((unsigned)(127 - E1) << 23);                      \
      rv.z = __uint_as_float((unsigned)(127 - E2) << 23);                      \
      rv.w = __uint_as_float((unsigned)(127 - E3) << 23);                      \
      *(f32x4*)&r_s[khi << 2] = rv;                                            \
    }                                                                          \
    bar_lgkm();                                                                \
  } while (0)

  // main: groups of 4 starting at t=1 (phases 1,2,2,0); buffers (1,0)/(0,1);
  // prefetch sets alternate A/B. Tail: 509 (APPLY), 510, 511 (PLAIN).
  for (int t = 1; t <= Lc - 4; t += 4) {
    STEP(t,     1, 0, 1, xA0, xA1, xA2, xA3);
    STEP(t + 1, 0, 1, 2, xB0, xB1, xB2, xB3);
    STEP(t + 2, 1, 0, 2, xA0, xA1, xA2, xA3);
    STEP(t + 3, 0, 1, 0, xB0, xB1, xB2, xB3);
  }
  STEP(Lc - 3, 1, 0, 1, xA0, xA1, xA2, xA3);
  STEP(Lc - 2, 0, 1, 2, xB0, xB1, xB2, xB3);
  STEP(Lc - 1, 1, 0, 2, xA0, xA1, xA2, xA3);
#undef STEP
#undef MFMA_

  // ---- logZ_b = c_b + log(sum_j Abar[b][j] * exp(end[j])) ----
  if (rlane) *(f32x4*)&c_s[khi << 2] = c;
  float eex = __expf(endT[jloc]);
  float s0 = Ao0 * eex, s1 = Ao1 * eex, s2 = Ao2 * eex, s3 = Ao3 * eex;
#pragma unroll
  for (int off = 1; off < 16; off <<= 1) {
    s0 += __shfl_xor(s0, off);
    s1 += __shfl_xor(s1, off);
    s2 += __shfl_xor(s2, off);
    s3 += __shfl_xor(s3, off);
  }
  if (crow == 0) {
    red[4 * khi + 0][w] = s0;
    red[4 * khi + 1][w] = s1;
    red[4 * khi + 2][w] = s2;
    red[4 * khi + 3][w] = s3;
  }
  __syncthreads();
  if (tid < GB) {
    float tot = 0.f;
#pragma unroll
    for (int ww = 0; ww < NW; ++ww) tot += red[tid][ww];
    float logZ = c_s[tid] + __logf(tot);
    diff_out[bg0 + tid] = logZ - score_s[tid];
    msum_out[bg0 + tid] = msum_s[tid];
  }
}

__global__ __launch_bounds__(512)
void crf_final(const float* __restrict__ diff, const float* __restrict__ msum,
               float* __restrict__ out)
{
  __shared__ float sd[512];
  __shared__ float sm[512];
  int t = threadIdx.x;
  sd[t] = diff[t];
  sm[t] = msum[t];
  __syncthreads();
  for (int s = 256; s > 0; s >>= 1) {
    if (t < s) { sd[t] += sd[t + s]; sm[t] += sm[t + s]; }
    __syncthreads();
  }
  if (t == 0) out[0] = sd[0] / sm[0];
}

extern "C" void kernel_launch(void* const* d_in, const int* in_sizes, int n_in,
                              void* d_out, int out_size, void* d_ws, size_t ws_size,
                              hipStream_t stream) {
  const float* x      = (const float*)d_in[0];
  const float* trans  = (const float*)d_in[1];
  const float* startT = (const float*)d_in[2];
  const float* endT   = (const float*)d_in[3];
  const int*   labels = (const int*)d_in[4];
  const int*   mask   = (const int*)d_in[5];
  float* out = (float*)d_out;
  float* ws  = (float*)d_ws;
  float* diff = ws;        // [512]
  float* msum = ws + Bc;   // [512]

  crf_forward<<<dim3(Bc / GB), dim3(512), 0, stream>>>(
      x, trans, startT, endT, labels, mask, diff, msum);
  crf_final<<<dim3(1), dim3(512), 0, stream>>>(diff, msum, out);
}

// Round 14
// 171.797 us; speedup vs baseline: 2.6861x; 1.1517x over previous
//
#include <hip/hip_runtime.h>
#include <hip/hip_bf16.h>

#define Bc 512
#define Lc 512
#define Tc 128
#define GB 16     // batches per block
#define NW 8      // waves per block

typedef __attribute__((ext_vector_type(8))) short bf16x8;
typedef __attribute__((ext_vector_type(4))) float f32x4;
typedef __attribute__((ext_vector_type(2))) unsigned u32x2;

// raw barrier: drain LDS ops only; global prefetches stay in flight
__device__ __forceinline__ void bar_lgkm() {
  asm volatile("s_waitcnt lgkmcnt(0)\n\ts_barrier" ::: "memory");
}
__device__ __forceinline__ unsigned short f2bf_u(float f) {
  __hip_bfloat16 h = __float2bfloat16(f);
  unsigned short us;
  __builtin_memcpy(&us, &h, 2);
  return us;
}
__device__ __forceinline__ short f2bf(float f) { return (short)f2bf_u(f); }
__device__ __forceinline__ unsigned pk2(float a, float b) {
  return (unsigned)f2bf_u(a) | ((unsigned)f2bf_u(b) << 16);
}

__global__ __launch_bounds__(512, 1)
void crf_forward(const float* __restrict__ x,      // [B,L,T]
                 const float* __restrict__ trans,  // [T,T]
                 const float* __restrict__ startT, // [T]
                 const float* __restrict__ endT,   // [T]
                 const int*   __restrict__ labels, // [B,L]
                 const int*   __restrict__ mask,   // [B,L]
                 float* __restrict__ diff_out,     // [B]
                 float* __restrict__ msum_out)     // [B]
{
  // Abar bf16, swizzled: elem(b, j) = b*128 + (j ^ ((b&7)<<3)); double-buffered
  __shared__ __align__(16) unsigned short Pl[2][GB * Tc];
  __shared__ __align__(16) float r_s[GB];   // per-batch rescale bcast
  __shared__ unsigned char anyz[Lc];        // any mask==0 at t
  __shared__ __align__(16) float c_s[GB];
  __shared__ float score_s[GB];
  __shared__ float msum_s[GB];
  __shared__ float red[GB][NW];

  const int tid  = threadIdx.x;
  const int lane = tid & 63;
  const int w    = tid >> 6;        // wave 0..7 owns j-tile [16w,16w+16)
  const int crow = lane & 15;       // A-operand: j-row-in-tile; B/C: batch
  const int khi  = lane >> 4;       // 0..3
  const int bg0  = blockIdx.x * GB;
  const bool rl  = (w == 0) && (khi == 0);  // 16 lanes own r/c for batch=crow

  // ---- stage anyz flags (one-time) ----
  if (tid < Lc) {
    unsigned zz = 0;
    for (int bb = 0; bb < GB; ++bb)
      zz |= (unsigned)(mask[(size_t)(bg0 + bb) * Lc + tid] == 0);
    anyz[tid] = (unsigned char)zz;
  }

  // ---- gold-path score + msum: wave w handles local batches 2w, 2w+1 ----
  for (int bb = 2 * w; bb < 2 * w + 2; ++bb) {
    const int bglob = bg0 + bb;
    const int* lbp = labels + (size_t)bglob * Lc;
    const int* mkp = mask + (size_t)bglob * Lc;
    const float* xrow = x + (size_t)bglob * Lc * Tc;
    float sp = 0.f, msp = 0.f;
    for (int t = lane; t < Lc; t += 64) {
      int l0 = lbp[t];
      int m0 = mkp[t];
      msp += (float)m0;
      if (t < Lc - 1) {
        int l1 = lbp[t + 1];
        float m1 = (float)mkp[t + 1];
        sp += trans[l0 * Tc + l1] * m1 + xrow[(size_t)t * Tc + l0] * (float)m0;
      }
    }
#pragma unroll
    for (int off = 32; off; off >>= 1) {
      sp += __shfl_xor(sp, off);
      msp += __shfl_xor(msp, off);
    }
    if (lane == 0) {
      int last_idx = (int)msp - 1;
      int lt = lbp[last_idx];
      score_s[bb] = sp + startT[lbp[0]] + endT[lt]
                  + xrow[(size_t)(Lc - 1) * Tc + lt] * (float)mkp[Lc - 1];
      msum_s[bb] = msp;
    }
  }

  // ---- E^T fragments (A-operand): lane holds A[row=crow][k=32Q+8khi+e]
  //      = E[k][16w+crow] = exp(trans[k*128 + 16w+crow]); 16 VGPRs ----
  bf16x8 Ef0, Ef1, Ef2, Ef3;
  {
    const int jr = 16 * w + crow;
#pragma unroll
    for (int e = 0; e < 8; ++e) Ef0[e] = f2bf(__expf(trans[(     8 * khi + e) * Tc + jr]));
#pragma unroll
    for (int e = 0; e < 8; ++e) Ef1[e] = f2bf(__expf(trans[(32 + 8 * khi + e) * Tc + jr]));
#pragma unroll
    for (int e = 0; e < 8; ++e) Ef2[e] = f2bf(__expf(trans[(64 + 8 * khi + e) * Tc + jr]));
#pragma unroll
    for (int e = 0; e < 8; ++e) Ef3[e] = f2bf(__expf(trans[(96 + 8 * khi + e) * Tc + jr]));
  }

  // ---- per-lane constant offsets ----
  const int sw   = (crow & 7) << 3;           // XOR swizzle key (elem units)
  const int boff = crow * Tc;
  const int ro0  = boff + (( 0 + 8 * khi) ^ sw);  // B-frag b128 reads
  const int ro1  = boff + ((32 + 8 * khi) ^ sw);
  const int ro2  = boff + ((64 + 8 * khi) ^ sw);
  const int ro3  = boff + ((96 + 8 * khi) ^ sw);
  const int wo   = boff + ((16 * w + 4 * khi) ^ sw);  // b64 packed store
  // x: lane reads x[b=crow][t][16w+4khi .. +3] as one f32x4
  const float* xp = x + (size_t)(bg0 + crow) * Lc * Tc + 16 * w + 4 * khi;
  const int*   mkl = mask + (size_t)(bg0 + crow) * Lc;  // per-lane mask row

  __syncthreads();  // anyz staged

  // ---- init: alpha_0 = start + x_0; exact renorm by alpha_0[b][0] ----
  f32x4 st4 = *(const f32x4*)&startT[16 * w + 4 * khi];
  f32x4 a0  = st4 + *(const f32x4*)xp;
  if (rl) r_s[crow] = a0.x;         // rl lanes have j0 = 0
  __syncthreads();
  float cb = r_s[crow];
  f32x4 Ao;
  Ao.x = __expf(a0.x - cb); Ao.y = __expf(a0.y - cb);
  Ao.z = __expf(a0.z - cb); Ao.w = __expf(a0.w - cb);
  {
    u32x2 pv = {pk2(Ao.x, Ao.y), pk2(Ao.z, Ao.w)};
    *(u32x2*)&Pl[1][wo] = pv;
  }
  float c  = rl ? cb : 0.f;
  float lr = 0.f;                   // pending c-increment for next APPLY
  __syncthreads();                  // cb consumed -> safe to overwrite r_s
  if (rl) r_s[crow] = 1.f;          // first APPLY multiplies by 1
  // ---- depth-2 x prefetch ----
  f32x4 xA = *(const f32x4*)(xp + 1 * Tc);
  f32x4 xB = *(const f32x4*)(xp + 2 * Tc);
  __syncthreads();                  // Pl[1], r_s visible

  // Phases: 1=APPLY (read r_s, scale, c+=lr), 2=PLAIN, 0=COMPUTE (rl lanes:
  // exponent of new Abar[b][0] -> r_s, lr). az: rare general-mask path.
#define MFMA_(A, B, C_) C_ = __builtin_amdgcn_mfma_f32_16x16x32_bf16(A, B, C_, 0, 0, 0)
#define STEP(T, RB, WB, PH, XQ) do {                                           \
    bf16x8 Bf0 = *(const bf16x8*)&Pl[RB][ro0];                                 \
    bf16x8 Bf1 = *(const bf16x8*)&Pl[RB][ro1];                                 \
    bf16x8 Bf2 = *(const bf16x8*)&Pl[RB][ro2];                                 \
    bf16x8 Bf3 = *(const bf16x8*)&Pl[RB][ro3];                                 \
    unsigned char az = anyz[T];                                                \
    f32x4 ex;                                                                  \
    ex.x = __expf(XQ.x); ex.y = __expf(XQ.y);                                  \
    ex.z = __expf(XQ.z); ex.w = __expf(XQ.w);                                  \
    { int tp__ = (T) + 2; if (tp__ > Lc - 1) tp__ = Lc - 1;                    \
      XQ = *(const f32x4*)(xp + (size_t)tp__ * Tc); }                          \
    f32x4 Ca = {0.f, 0.f, 0.f, 0.f};                                           \
    f32x4 Cb2 = {0.f, 0.f, 0.f, 0.f};                                          \
    MFMA_(Ef0, Bf0, Ca);  MFMA_(Ef2, Bf2, Cb2);                                \
    MFMA_(Ef1, Bf1, Ca);  MFMA_(Ef3, Bf3, Cb2);                                \
    f32x4 Cr = Ca + Cb2;                                                       \
    f32x4 v;                                                                   \
    if ((PH) == 1) {                                                           \
      float rr = r_s[crow];                                                    \
      v.x = Cr.x * rr * ex.x; v.y = Cr.y * rr * ex.y;                          \
      v.z = Cr.z * rr * ex.z; v.w = Cr.w * rr * ex.w;                          \
    } else {                                                                   \
      v.x = Cr.x * ex.x; v.y = Cr.y * ex.y;                                    \
      v.z = Cr.z * ex.z; v.w = Cr.w * ex.w;                                    \
    }                                                                          \
    if (az) {  /* rare general-mask path (per-lane batch -> uniform blend) */  \
      int m = mkl[T];                                                          \
      Ao.x = m ? v.x : Ao.x; Ao.y = m ? v.y : Ao.y;                            \
      Ao.z = m ? v.z : Ao.z; Ao.w = m ? v.w : Ao.w;                            \
      if ((PH) == 1 && rl) c += m ? lr : 0.f;                                  \
    } else {                                                                   \
      Ao = v;                                                                  \
      if ((PH) == 1 && rl) c += lr;                                            \
    }                                                                          \
    {                                                                          \
      u32x2 pv = {pk2(Ao.x, Ao.y), pk2(Ao.z, Ao.w)};                           \
      *(u32x2*)&Pl[WB][wo] = pv;                                               \
    }                                                                          \
    if ((PH) == 0 && rl) {  /* COMPUTE: exponent of new Abar[b][0] */          \
      int E0 = (int)((__float_as_uint(Ao.x) >> 23) & 0xffu) - 127;             \
      lr = (float)E0 * 0.6931471805599453f;                                    \
      r_s[crow] = __uint_as_float((unsigned)(127 - E0) << 23);                 \
    }                                                                          \
    bar_lgkm();                                                                \
  } while (0)

  // main: groups of 4 (phases 1,2,2,0); tail 509 (APPLY), 510, 511 (PLAIN)
  for (int t = 1; t <= Lc - 4; t += 4) {
    STEP(t,     1, 0, 1, xA);
    STEP(t + 1, 0, 1, 2, xB);
    STEP(t + 2, 1, 0, 2, xA);
    STEP(t + 3, 0, 1, 0, xB);
  }
  STEP(Lc - 3, 1, 0, 1, xA);
  STEP(Lc - 2, 0, 1, 2, xB);
  STEP(Lc - 1, 1, 0, 2, xA);
#undef STEP
#undef MFMA_

  // ---- logZ_b = c_b + log(sum_j Abar[b][j] * exp(end[j])) ----
  if (rl) c_s[crow] = c;
  f32x4 ev = *(const f32x4*)&endT[16 * w + 4 * khi];
  float part = Ao.x * __expf(ev.x) + Ao.y * __expf(ev.y)
             + Ao.z * __expf(ev.z) + Ao.w * __expf(ev.w);
  part += __shfl_xor(part, 16);
  part += __shfl_xor(part, 32);
  if (khi == 0) red[crow][w] = part;
  __syncthreads();
  if (tid < GB) {
    float tot = 0.f;
#pragma unroll
    for (int ww = 0; ww < NW; ++ww) tot += red[tid][ww];
    float logZ = c_s[tid] + __logf(tot);
    diff_out[bg0 + tid] = logZ - score_s[tid];
    msum_out[bg0 + tid] = msum_s[tid];
  }
}

__global__ __launch_bounds__(512)
void crf_final(const float* __restrict__ diff, const float* __restrict__ msum,
               float* __restrict__ out)
{
  __shared__ float sd[512];
  __shared__ float sm[512];
  int t = threadIdx.x;
  sd[t] = diff[t];
  sm[t] = msum[t];
  __syncthreads();
  for (int s = 256; s > 0; s >>= 1) {
    if (t < s) { sd[t] += sd[t + s]; sm[t] += sm[t + s]; }
    __syncthreads();
  }
  if (t == 0) out[0] = sd[0] / sm[0];
}

extern "C" void kernel_launch(void* const* d_in, const int* in_sizes, int n_in,
                              void* d_out, int out_size, void* d_ws, size_t ws_size,
                              hipStream_t stream) {
  const float* x      = (const float*)d_in[0];
  const float* trans  = (const float*)d_in[1];
  const float* startT = (const float*)d_in[2];
  const float* endT   = (const float*)d_in[3];
  const int*   labels = (const int*)d_in[4];
  const int*   mask   = (const int*)d_in[5];
  float* out = (float*)d_out;
  float* ws  = (float*)d_ws;
  float* diff = ws;        // [512]
  float* msum = ws + Bc;   // [512]

  crf_forward<<<dim3(Bc / GB), dim3(512), 0, stream>>>(
      x, trans, startT, endT, labels, mask, diff, msum);
  crf_final<<<dim3(1), dim3(512), 0, stream>>>(diff, msum, out);
}